// Round 4
// baseline (560.558 us; speedup 1.0000x reference)
//
#include <hip/hip_runtime.h>
#include <hip/hip_bf16.h>
#include <cmath>

typedef unsigned short ushortT;
typedef unsigned int u32;
typedef __attribute__((ext_vector_type(8))) short short8;
typedef __attribute__((ext_vector_type(4))) float floatx4;

#define IMG 14
#define NTOK 196          // 14*14
#define BATCH 64
#define M_TOT 12544       // 64*196
#define M_HALF 6272       // 49*128
#define INCH 384
#define OUTCH 768
#define HIDDEN 1536
#define HEADS 8
#define HDIM 32

__device__ __forceinline__ float b2f(ushortT u) {
    union { u32 i; float f; } v; v.i = ((u32)u) << 16; return v.f;
}
__device__ __forceinline__ ushortT f2b(float f) {
    union { float f; u32 i; } v; v.f = f;
    u32 r = v.i + 0x7FFFu + ((v.i >> 16) & 1u);
    return (ushortT)(r >> 16);
}

// ---------------------------------------------------------------- fp32 -> bf16 elementwise
// n must be a multiple of 1024 (launch 256 threads, each converts 4).
__global__ void convert_k(const float* __restrict__ in, ushortT* __restrict__ out) {
    int i = (blockIdx.x * 256 + threadIdx.x) * 4;
    float4 v = *(const float4*)(in + i);
    ushortT o[4] = { f2b(v.x), f2b(v.y), f2b(v.z), f2b(v.w) };
    *(uint2*)(out + i) = *(const uint2*)o;
}

// ---------------------------------------------------------------- transpose + fp32->bf16
// in float [R][C] -> out bf16 [C][R]; R,C multiples of 32. block 256, grid (C/32, R/32).
__global__ void transpose_k(const float* __restrict__ in, ushortT* __restrict__ out,
                            int R, int C) {
    __shared__ ushortT t[32][33];
    int bx = blockIdx.x * 32, by = blockIdx.y * 32;
    int tx = threadIdx.x & 31, ty = threadIdx.x >> 5;  // ty in [0,8)
    #pragma unroll
    for (int i = 0; i < 4; ++i) {
        int r = by + ty * 4 + i;
        t[ty * 4 + i][tx] = f2b(in[(size_t)r * C + bx + tx]);
    }
    __syncthreads();
    #pragma unroll
    for (int i = 0; i < 4; ++i) {
        int r = bx + ty * 4 + i;
        out[(size_t)r * R + by + tx] = t[tx][ty * 4 + i];
    }
}

// ---------------------------------------------------------------- maxpool 3x3 s2 p1
// x float [64][384][28][28] -> pooled bf16 token-major [12544][384]
__global__ void pool_kernel(const float* __restrict__ x, ushortT* __restrict__ pooled) {
    int cg = blockIdx.x, b = blockIdx.y;
    int c0 = cg * 8;
    __shared__ float xs[8 * 784];
    const float4* src = (const float4*)(x + ((size_t)b * INCH + c0) * 784);
    float4* dst4 = (float4*)xs;
    for (int i = threadIdx.x; i < 1568; i += 256) dst4[i] = src[i];
    __syncthreads();
    for (int o = threadIdx.x; o < 8 * NTOK; o += 256) {
        int p = o / NTOK, n = o - p * NTOK;
        int hh = n / IMG, ww = n - hh * IMG;
        int y0 = hh * 2, x0 = ww * 2;
        int ya = (y0 == 0) ? 0 : y0 - 1;
        int xa = (x0 == 0) ? 0 : x0 - 1;
        int yb = y0 + 1, xb = x0 + 1;   // <= 27 always
        float mv = -1e30f;
        for (int y = ya; y <= yb; ++y)
            for (int xx = xa; xx <= xb; ++xx)
                mv = fmaxf(mv, xs[p * 784 + y * 28 + xx]);
        pooled[((size_t)b * NTOK + n) * INCH + c0 + p] = f2b(mv);
    }
}

// ---------------------------------------------------------------- layernorm
// in bf16, gamma/beta fp32, out bf16. block = C/3 threads, one block per token row.
__global__ void ln_kernel(const ushortT* __restrict__ in, const float* __restrict__ gw,
                          const float* __restrict__ bw, ushortT* __restrict__ out, int C) {
    int m = blockIdx.x;
    int t = threadIdx.x, B = blockDim.x;
    const ushortT* row = in + (size_t)m * C;
    float v[3];
    #pragma unroll
    for (int i = 0; i < 3; ++i) v[i] = b2f(row[t + i * B]);
    float s = v[0] + v[1] + v[2];
    float q = v[0] * v[0] + v[1] * v[1] + v[2] * v[2];
    #pragma unroll
    for (int off = 32; off > 0; off >>= 1) {
        s += __shfl_down(s, off, 64);
        q += __shfl_down(q, off, 64);
    }
    __shared__ float red[8][2];
    int wv = t >> 6, ln = t & 63, nw = B >> 6;
    if (ln == 0) { red[wv][0] = s; red[wv][1] = q; }
    __syncthreads();
    if (t == 0) {
        float ts = 0.f, tq = 0.f;
        for (int w = 0; w < nw; ++w) { ts += red[w][0]; tq += red[w][1]; }
        red[0][0] = ts; red[0][1] = tq;
    }
    __syncthreads();
    float mu = red[0][0] / (float)C;
    float var = red[0][1] / (float)C - mu * mu;
    float rs = rsqrtf(var + 1e-5f);
    #pragma unroll
    for (int i = 0; i < 3; ++i) {
        int c = t + i * B;
        out[(size_t)m * C + c] = f2b((v[i] - mu) * rs * gw[c] + bw[c]);
    }
}

// ---------------------------------------------------------------- attention
// qkv bf16 [3][64][8][196][32], bias_table fp32 [729][8]. one block per (b,h).
__global__ __launch_bounds__(256) void attn_kernel(const ushortT* __restrict__ qkv,
                                                   const float* __restrict__ bias_table,
                                                   ushortT* __restrict__ attn_out) {
    int bh = blockIdx.x;
    int b = bh >> 3, h = bh & 7;
    __shared__ float Ks[NTOK * HDIM];
    __shared__ float Vs[NTOK * HDIM];
    const ushortT* kb = qkv + (size_t)(512 + bh) * (NTOK * HDIM);
    const ushortT* vb = qkv + (size_t)(1024 + bh) * (NTOK * HDIM);
    for (int i = threadIdx.x; i < NTOK * HDIM; i += 256) {
        Ks[i] = b2f(kb[i]);
        Vs[i] = b2f(vb[i]);
    }
    __syncthreads();
    int i = threadIdx.x;
    if (i >= NTOK) return;
    const ushortT* qb = qkv + (size_t)bh * (NTOK * HDIM) + i * HDIM;
    float qr[32];
    #pragma unroll
    for (int d = 0; d < 32; ++d) qr[d] = b2f(qb[d]) * 0.17677669529663687f;
    int iy = i / IMG, ix = i - iy * IMG;
    int ibase = ((iy + 13) * 27 + (ix + 13)) * 8 + h;
    float O[32];
    #pragma unroll
    for (int d = 0; d < 32; ++d) O[d] = 0.f;
    float mmax = -1e30f, l = 0.f;
    int jy = 0, jx = 0;
    for (int j = 0; j < NTOK; ++j) {
        const float4* kr = (const float4*)(Ks + j * 32);
        float s = 0.f;
        #pragma unroll
        for (int t4 = 0; t4 < 8; ++t4) {
            float4 kk = kr[t4];
            s += qr[t4 * 4] * kk.x + qr[t4 * 4 + 1] * kk.y +
                 qr[t4 * 4 + 2] * kk.z + qr[t4 * 4 + 3] * kk.w;
        }
        s += bias_table[ibase - (jy * 27 + jx) * 8];
        if (++jx == IMG) { jx = 0; ++jy; }
        if (s > mmax) {
            float sc = __expf(mmax - s);
            mmax = s;
            l *= sc;
            #pragma unroll
            for (int d = 0; d < 32; ++d) O[d] *= sc;
        }
        float p = __expf(s - mmax);
        l += p;
        const float4* vr = (const float4*)(Vs + j * 32);
        #pragma unroll
        for (int t4 = 0; t4 < 8; ++t4) {
            float4 vv = vr[t4];
            O[t4 * 4]     += p * vv.x;
            O[t4 * 4 + 1] += p * vv.y;
            O[t4 * 4 + 2] += p * vv.z;
            O[t4 * 4 + 3] += p * vv.w;
        }
    }
    float inv = 1.f / l;
    ushortT* dst = attn_out + ((size_t)(b * NTOK + i)) * 256 + h * 32;
    #pragma unroll
    for (int d = 0; d < 32; ++d) dst[d] = f2b(O[d] * inv);
}

// ---------------------------------------------------------------- GEMM 128x128, BK=32
// A bf16 [M,K] row-major, B bf16 [N,K] row-major. 256 threads, 4 waves 2x2.
// Register-staged LDS. bias fp32.
// EPI: 0 = qkv scatter(bf16), 1 = +bias -> htok(bf16), 2 = +bias+gelu -> mid(bf16),
//      3 = +bias+addend(bf16) -> d_out fp32 transposed
template <int EPI, typename OUT_T>
__global__ __launch_bounds__(256) void gemm128(
    const ushortT* __restrict__ A1, const ushortT* __restrict__ B1, int K1,
    const ushortT* __restrict__ A2, const ushortT* __restrict__ B2, int K2,
    const float* __restrict__ bias, const ushortT* __restrict__ addend,
    OUT_T* __restrict__ out, int m_off) {
    __shared__ ushortT As[128 * 32];
    __shared__ ushortT Bs[128 * 32];
    const int tid = threadIdx.x, wave = tid >> 6, lane = tid & 63;
    const int wm = wave & 1, wn = wave >> 1;
    const int tm = blockIdx.x, tn = blockIdx.y;

    floatx4 acc[4][4];
    #pragma unroll
    for (int a = 0; a < 4; ++a)
        #pragma unroll
        for (int c = 0; c < 4; ++c)
            acc[a][c] = (floatx4){0.f, 0.f, 0.f, 0.f};

    // staging decomposition: chunk c in [0,512): row = c>>2, kcol = (c&3)*8
    const int c0 = tid, c1 = tid + 256;
    const int row0s = c0 >> 2, kc0 = (c0 & 3) * 8;
    const int row1s = c1 >> 2, kc1 = (c1 & 3) * 8;
    // fragment read indices
    const int lrow_a = wm * 64 + (lane & 15);
    const int lrow_b = wn * 64 + (lane & 15);
    const int kof = (lane >> 4) * 8;

    auto kloop = [&](const ushortT* A, const ushortT* B, int K) {
        const size_t r0a = (size_t)tm * 128, r0b = (size_t)tn * 128;
        for (int k0 = 0; k0 < K; k0 += 32) {
            uint4 va0 = *(const uint4*)(A + (r0a + row0s) * K + k0 + kc0);
            uint4 va1 = *(const uint4*)(A + (r0a + row1s) * K + k0 + kc1);
            uint4 vb0 = *(const uint4*)(B + (r0b + row0s) * K + k0 + kc0);
            uint4 vb1 = *(const uint4*)(B + (r0b + row1s) * K + k0 + kc1);
            __syncthreads();   // previous iteration's LDS reads done
            *(uint4*)(As + row0s * 32 + kc0) = va0;
            *(uint4*)(As + row1s * 32 + kc1) = va1;
            *(uint4*)(Bs + row0s * 32 + kc0) = vb0;
            *(uint4*)(Bs + row1s * 32 + kc1) = vb1;
            __syncthreads();
            short8 af[4], bf[4];
            #pragma unroll
            for (int t = 0; t < 4; ++t) {
                af[t] = *(const short8*)(As + (lrow_a + t * 16) * 32 + kof);
                bf[t] = *(const short8*)(Bs + (lrow_b + t * 16) * 32 + kof);
            }
            #pragma unroll
            for (int mt = 0; mt < 4; ++mt)
                #pragma unroll
                for (int nt = 0; nt < 4; ++nt)
                    acc[mt][nt] = __builtin_amdgcn_mfma_f32_16x16x32_bf16(
                        af[mt], bf[nt], acc[mt][nt], 0, 0, 0);
        }
    };

    kloop(A1, B1, K1);
    if (B2) kloop(A2, B2, K2);

    const int nb = tn * 128 + wn * 64 + (lane & 15);
    const int mb = tm * 128 + wm * 64 + ((lane >> 4) << 2);
    #pragma unroll
    for (int nt = 0; nt < 4; ++nt) {
        int n = nb + nt * 16;
        float bv = (EPI == 0) ? 0.f : bias[n];
        #pragma unroll
        for (int mt = 0; mt < 4; ++mt) {
            #pragma unroll
            for (int r = 0; r < 4; ++r) {
                int m = mb + mt * 16 + r;
                float v = acc[mt][nt][r] + bv;
                if constexpr (EPI == 0) {
                    int bb = m / 196, tok = m - bb * 196;
                    int reg = n >> 8, head = (n >> 5) & 7, d = n & 31;
                    out[((size_t)((reg * 512 + bb * 8 + head) * 196 + tok)) * 32 + d] = f2b(v);
                } else if constexpr (EPI == 1) {
                    out[(size_t)m * 768 + n] = f2b(v);
                } else if constexpr (EPI == 2) {
                    float gl = 0.5f * v * (1.f + erff(v * 0.70710678118654752f));
                    out[(size_t)m * 1536 + n] = f2b(gl);
                } else {
                    v += b2f(addend[(size_t)m * 768 + n]);
                    int mg = m + m_off;
                    int bb = mg / 196, tok = mg - bb * 196;
                    out[((size_t)(bb * 768 + n)) * 196 + tok] = v;   // fp32 store
                }
            }
        }
    }
}

// ---------------------------------------------------------------- launch
extern "C" void kernel_launch(void* const* d_in, const int* in_sizes, int n_in,
                              void* d_out, int out_size, void* d_ws, size_t ws_size,
                              hipStream_t stream) {
    const float* x       = (const float*)d_in[0];
    const float* W_qkv   = (const float*)d_in[1];
    const float* bias_tb = (const float*)d_in[2];
    const float* W_out   = (const float*)d_in[3];
    const float* b_out   = (const float*)d_in[4];
    const float* ln1_g   = (const float*)d_in[5];
    const float* ln1_b   = (const float*)d_in[6];
    const float* ln2_g   = (const float*)d_in[7];
    const float* ln2_b   = (const float*)d_in[8];
    const float* W_fc1   = (const float*)d_in[9];
    const float* b_fc1   = (const float*)d_in[10];
    const float* W_fc2   = (const float*)d_in[11];
    const float* b_fc2   = (const float*)d_in[12];
    const float* W_proj  = (const float*)d_in[13];
    float* out = (float*)d_out;

    char* ws = (char*)d_ws;
    // compact layout with region reuse; total footprint ~64.1 MB
    ushortT* pooled = (ushortT*)(ws);                 // [12544][384]   9,633,792 B
    ushortT* tln1   = (ushortT*)(ws + 9633792);       // [12544][384]   9,633,792 B
    ushortT* attno  = tln1;                           // reuse (tln1 dead after qkv gemm)
    ushortT* qkvb   = (ushortT*)(ws + 19267584);      // [3][64][8][196][32] 19,267,584 B
    ushortT* tln2   = qkvb;                           // reuse (qkvb dead after attn)
    ushortT* mid    = (ushortT*)(ws);                 // [6272][1536] (pooled+tln1 dead by FFN)
    ushortT* htok   = (ushortT*)(ws + 38535168);      // [12544][768] 19,267,584 B
    ushortT* wTqkv  = (ushortT*)(ws + 57802752);      // [768][384]
    ushortT* wTout  = wTqkv + 768 * 384;              // [768][256]
    ushortT* wTfc1  = wTout + 768 * 256;              // [1536][768]
    ushortT* wTfc2  = wTfc1 + 1536 * 768;             // [768][1536]
    ushortT* wProjB = wTfc2 + 768 * 1536;             // [768][384] (already [N][K], convert only)
    // end of ws use: 57,802,752 + 2*(294912+196608+1179648+1179648+294912) = 64,094,208 B

    // weight transposes ([K,N] fp32 -> [N,K] bf16)
    transpose_k<<<dim3(24, 12), 256, 0, stream>>>(W_qkv, wTqkv, 384, 768);
    transpose_k<<<dim3(24, 8), 256, 0, stream>>>(W_out, wTout, 256, 768);
    transpose_k<<<dim3(48, 24), 256, 0, stream>>>(W_fc1, wTfc1, 768, 1536);
    transpose_k<<<dim3(24, 48), 256, 0, stream>>>(W_fc2, wTfc2, 1536, 768);
    // W_proj [768][384] is already [N][K]; elementwise fp32->bf16 only.
    convert_k<<<288, 256, 0, stream>>>(W_proj, wProjB);   // 294912 = 288*1024 elements

    // pool + LN1
    pool_kernel<<<dim3(48, 64), 256, 0, stream>>>(x, pooled);
    ln_kernel<<<M_TOT, 128, 0, stream>>>(pooled, ln1_g, ln1_b, tln1, 384);

    // QKV gemm
    gemm128<0, ushortT><<<dim3(98, 6), 256, 0, stream>>>(tln1, wTqkv, 384,
                                                nullptr, nullptr, 0,
                                                nullptr, nullptr, qkvb, 0);
    attn_kernel<<<512, 256, 0, stream>>>(qkvb, bias_tb, attno);

    // h = attn_out @ W_out^T + pooled @ W_proj^T + b_out
    gemm128<1, ushortT><<<dim3(98, 6), 256, 0, stream>>>(attno, wTout, 256,
                                                pooled, wProjB, 384,
                                                b_out, nullptr, htok, 0);
    ln_kernel<<<M_TOT, 256, 0, stream>>>(htok, ln2_g, ln2_b, tln2, 768);

    // FFN in two M-halves (keeps mid buffer at 19.3 MB)
    for (int half = 0; half < 2; ++half) {
        const ushortT* a2 = tln2 + (size_t)half * M_HALF * 768;
        gemm128<2, ushortT><<<dim3(49, 12), 256, 0, stream>>>(a2, wTfc1, 768,
                                                     nullptr, nullptr, 0,
                                                     b_fc1, nullptr, mid, 0);
        gemm128<3, float><<<dim3(49, 6), 256, 0, stream>>>(mid, wTfc2, 1536,
                                                    nullptr, nullptr, 0,
                                                    b_fc2, htok + (size_t)half * M_HALF * 768,
                                                    out, half * M_HALF);
    }
    (void)in_sizes; (void)n_in; (void)out_size; (void)ws_size;
}

// Round 5
// 496.287 us; speedup vs baseline: 1.1295x; 1.1295x over previous
//
#include <hip/hip_runtime.h>
#include <hip/hip_bf16.h>
#include <cmath>

typedef unsigned short ushortT;
typedef unsigned int u32;
typedef __attribute__((ext_vector_type(8))) short short8;
typedef __attribute__((ext_vector_type(4))) float floatx4;
typedef __attribute__((ext_vector_type(2))) _Float16 half2v;
typedef __attribute__((ext_vector_type(8))) _Float16 half8v;

#define IMG 14
#define NTOK 196          // 14*14
#define BATCH 64
#define M_TOT 12544       // 64*196
#define M_HALF 6272       // 49*128
#define INCH 384
#define OUTCH 768
#define HIDDEN 1536
#define HEADS 8
#define HDIM 32

#if __has_builtin(__builtin_amdgcn_fdot2)
#define FDOT2(a, b, c) __builtin_amdgcn_fdot2((a), (b), (c), false)
#else
#define FDOT2(a, b, c) ((c) + (float)(a)[0] * (float)(b)[0] + (float)(a)[1] * (float)(b)[1])
#endif

__device__ __forceinline__ float b2f(ushortT u) {
    union { u32 i; float f; } v; v.i = ((u32)u) << 16; return v.f;
}
__device__ __forceinline__ ushortT f2b(float f) {
    union { float f; u32 i; } v; v.f = f;
    u32 r = v.i + 0x7FFFu + ((v.i >> 16) & 1u);
    return (ushortT)(r >> 16);
}

__device__ __forceinline__ void async_ld16(const void* g, void* l) {
    __builtin_amdgcn_global_load_lds(
        (const __attribute__((address_space(1))) u32*)g,
        (__attribute__((address_space(3))) u32*)l, 16, 0, 0);
}

// ---------------------------------------------------------------- fp32 -> bf16 elementwise
__global__ void convert_k(const float* __restrict__ in, ushortT* __restrict__ out) {
    int i = (blockIdx.x * 256 + threadIdx.x) * 4;
    float4 v = *(const float4*)(in + i);
    ushortT o[4] = { f2b(v.x), f2b(v.y), f2b(v.z), f2b(v.w) };
    *(uint2*)(out + i) = *(const uint2*)o;
}

// ---------------------------------------------------------------- transpose + fp32->bf16
// in float [R][C] -> out bf16 [C][R]; grid (C/32, R/32), block 256.
__global__ void transpose_k(const float* __restrict__ in, ushortT* __restrict__ out,
                            int R, int C) {
    __shared__ ushortT t[32][33];
    int bx = blockIdx.x * 32, by = blockIdx.y * 32;
    int tx = threadIdx.x & 31, ty = threadIdx.x >> 5;
    #pragma unroll
    for (int i = 0; i < 4; ++i) {
        int r = by + ty * 4 + i;
        t[ty * 4 + i][tx] = f2b(in[(size_t)r * C + bx + tx]);
    }
    __syncthreads();
    #pragma unroll
    for (int i = 0; i < 4; ++i) {
        int r = bx + ty * 4 + i;
        out[(size_t)r * R + by + tx] = t[tx][ty * 4 + i];
    }
}

// ---------------------------------------------------------------- maxpool 3x3 s2 p1
__global__ void pool_kernel(const float* __restrict__ x, ushortT* __restrict__ pooled) {
    int cg = blockIdx.x, b = blockIdx.y;
    int c0 = cg * 8;
    __shared__ float xs[8 * 784];
    const float4* src = (const float4*)(x + ((size_t)b * INCH + c0) * 784);
    float4* dst4 = (float4*)xs;
    for (int i = threadIdx.x; i < 1568; i += 256) dst4[i] = src[i];
    __syncthreads();
    for (int o = threadIdx.x; o < 8 * NTOK; o += 256) {
        int p = o / NTOK, n = o - p * NTOK;
        int hh = n / IMG, ww = n - hh * IMG;
        int y0 = hh * 2, x0 = ww * 2;
        int ya = (y0 == 0) ? 0 : y0 - 1;
        int xa = (x0 == 0) ? 0 : x0 - 1;
        int yb = y0 + 1, xb = x0 + 1;
        float mv = -1e30f;
        for (int y = ya; y <= yb; ++y)
            for (int xx = xa; xx <= xb; ++xx)
                mv = fmaxf(mv, xs[p * 784 + y * 28 + xx]);
        pooled[((size_t)b * NTOK + n) * INCH + c0 + p] = f2b(mv);
    }
}

// ---------------------------------------------------------------- layernorm
__global__ void ln_kernel(const ushortT* __restrict__ in, const float* __restrict__ gw,
                          const float* __restrict__ bw, ushortT* __restrict__ out, int C) {
    int m = blockIdx.x;
    int t = threadIdx.x, B = blockDim.x;
    const ushortT* row = in + (size_t)m * C;
    float v[3];
    #pragma unroll
    for (int i = 0; i < 3; ++i) v[i] = b2f(row[t + i * B]);
    float s = v[0] + v[1] + v[2];
    float q = v[0] * v[0] + v[1] * v[1] + v[2] * v[2];
    #pragma unroll
    for (int off = 32; off > 0; off >>= 1) {
        s += __shfl_down(s, off, 64);
        q += __shfl_down(q, off, 64);
    }
    __shared__ float red[8][2];
    int wv = t >> 6, ln = t & 63, nw = B >> 6;
    if (ln == 0) { red[wv][0] = s; red[wv][1] = q; }
    __syncthreads();
    if (t == 0) {
        float ts = 0.f, tq = 0.f;
        for (int w = 0; w < nw; ++w) { ts += red[w][0]; tq += red[w][1]; }
        red[0][0] = ts; red[0][1] = tq;
    }
    __syncthreads();
    float mu = red[0][0] / (float)C;
    float var = red[0][1] / (float)C - mu * mu;
    float rs = rsqrtf(var + 1e-5f);
    #pragma unroll
    for (int i = 0; i < 3; ++i) {
        int c = t + i * B;
        out[(size_t)m * C + c] = f2b((v[i] - mu) * rs * gw[c] + bw[c]);
    }
}

// ---------------------------------------------------------------- attention (f16 + fdot2, j-pairs)
// qkv bf16 [3][64][8][196][32], bias_table fp32 [729][8]. one block per (b,h).
// Scores are bounded (|s| ~ O(1)); softmax computed without max-shift (shift-invariant).
__global__ __launch_bounds__(256) void attn_kernel(const ushortT* __restrict__ qkv,
                                                   const float* __restrict__ bias_table,
                                                   ushortT* __restrict__ attn_out) {
    int bh = blockIdx.x;
    int b = bh >> 3, h = bh & 7;
    __shared__ _Float16 Kh[NTOK * HDIM];        // [196][32] f16 row-major
    __shared__ half2v  Vp[(NTOK / 2) * HDIM];   // Vp[jp*32+d] = (V[2jp][d], V[2jp+1][d])
    const ushortT* kb = qkv + (size_t)(512 + bh) * (NTOK * HDIM);
    const ushortT* vb = qkv + (size_t)(1024 + bh) * (NTOK * HDIM);
    // K: convert bf16 pairs -> half2 (b32 stores)
    {
        const u32* kb32 = (const u32*)kb;
        half2v* Kh2 = (half2v*)Kh;
        for (int idx = threadIdx.x; idx < NTOK * HDIM / 2; idx += 256) {
            u32 w = kb32[idx];
            half2v p;
            p[0] = (_Float16)b2f((ushortT)(w & 0xFFFFu));
            p[1] = (_Float16)b2f((ushortT)(w >> 16));
            Kh2[idx] = p;
        }
        for (int idx = threadIdx.x; idx < (NTOK / 2) * HDIM; idx += 256) {
            int jp = idx >> 5, d = idx & 31;
            half2v p;
            p[0] = (_Float16)b2f(vb[jp * 64 + d]);
            p[1] = (_Float16)b2f(vb[jp * 64 + 32 + d]);
            Vp[idx] = p;
        }
    }
    __syncthreads();
    int i = threadIdx.x;
    if (i >= NTOK) return;
    const ushortT* qb = qkv + (size_t)bh * (NTOK * HDIM) + i * HDIM;
    half2v qh[16];
    #pragma unroll
    for (int t = 0; t < 16; ++t) {
        qh[t][0] = (_Float16)(b2f(qb[2 * t]) * 0.17677669529663687f);
        qh[t][1] = (_Float16)(b2f(qb[2 * t + 1]) * 0.17677669529663687f);
    }
    int iy = i / IMG, ix = i - iy * IMG;
    int ibase = ((iy + 13) * 27 + (ix + 13)) * 8 + h;
    float O[32];
    #pragma unroll
    for (int d = 0; d < 32; ++d) O[d] = 0.f;
    float l = 0.f;
    int jy = 0, jx = 0;
    union h8 { half8v v8; half2v v2[4]; };
    for (int jp = 0; jp < NTOK / 2; ++jp) {
        const _Float16* k0p = Kh + (2 * jp) * 32;
        float s0 = 0.f, s1 = 0.f;
        #pragma unroll
        for (int c = 0; c < 4; ++c) {
            h8 u0, u1;
            u0.v8 = *(const half8v*)(k0p + c * 8);
            u1.v8 = *(const half8v*)(k0p + 32 + c * 8);
            #pragma unroll
            for (int t = 0; t < 4; ++t) {
                s0 = FDOT2(qh[c * 4 + t], u0.v2[t], s0);
                s1 = FDOT2(qh[c * 4 + t], u1.v2[t], s1);
            }
        }
        float b0 = bias_table[ibase - (jy * 27 + jx) * 8];
        if (++jx == IMG) { jx = 0; ++jy; }
        float b1 = bias_table[ibase - (jy * 27 + jx) * 8];
        if (++jx == IMG) { jx = 0; ++jy; }
        float p0 = __expf(s0 + b0);
        float p1 = __expf(s1 + b1);
        l += p0 + p1;
        half2v pp;
        pp[0] = (_Float16)p0;
        pp[1] = (_Float16)p1;
        const _Float16* vp = (const _Float16*)(Vp + jp * 32);
        #pragma unroll
        for (int c = 0; c < 8; ++c) {
            h8 uv;
            uv.v8 = *(const half8v*)(vp + c * 8);
            #pragma unroll
            for (int t = 0; t < 4; ++t)
                O[c * 4 + t] = FDOT2(pp, uv.v2[t], O[c * 4 + t]);
        }
    }
    float inv = 1.f / l;
    ushortT* dst = attn_out + ((size_t)(b * NTOK + i)) * 256 + h * 32;
    #pragma unroll
    for (int d = 0; d < 32; ++d) dst[d] = f2b(O[d] * inv);
}

// ---------------------------------------------------------------- GEMM BM=64 x BN, BK=32
// A bf16 [M,K], B bf16 [N,K]. 256 threads. global_load_lds (16B) staging.
// BN=128: waves 1x4 (wave = n-col strip of 32), per-wave acc 4x2 tiles.
// BN=64 : waves 2x2 (wm=wave&1 -> m strip 32, wn=wave>>1 -> n strip 32), acc 2x2.
// EPI: 0 = qkv scatter(bf16), 1 = +bias -> htok(bf16), 2 = +bias+gelu -> mid(bf16),
//      3 = +bias+addend(bf16) -> d_out fp32 transposed
template <int BN, int EPI, typename OUT_T>
__global__ __launch_bounds__(256) void gemm64(
    const ushortT* __restrict__ A1, const ushortT* __restrict__ B1, int K1,
    const ushortT* __restrict__ A2, const ushortT* __restrict__ B2, int K2,
    const float* __restrict__ bias, const ushortT* __restrict__ addend,
    OUT_T* __restrict__ out, int m_off) {
    __shared__ ushortT As[64 * 32];
    __shared__ ushortT Bs[BN * 32];
    const int tid = threadIdx.x, wave = tid >> 6, lane = tid & 63;
    constexpr int MT = (BN == 128) ? 4 : 2;
    constexpr int NT = 2;
    const int wmo = (BN == 128) ? 0 : (wave & 1) * 32;
    const int wno = (BN == 128) ? wave * 32 : (wave >> 1) * 32;
    const int tm = blockIdx.x, tn = blockIdx.y;

    floatx4 acc[MT][NT];
    #pragma unroll
    for (int a = 0; a < MT; ++a)
        #pragma unroll
        for (int c = 0; c < NT; ++c)
            acc[a][c] = (floatx4){0.f, 0.f, 0.f, 0.f};

    const int glrow = lane >> 2, glcol = (lane & 3) * 8;   // staging: 16 rows / issue
    const int kof = (lane >> 4) * 8;

    auto stage = [&](const ushortT* G, int ld, int row0, int k0, ushortT* S, int R16) {
        for (int i = wave; i < R16; i += 4)
            async_ld16(G + (size_t)(row0 + i * 16 + glrow) * ld + k0 + glcol, S + i * 512);
    };

    auto kloop = [&](const ushortT* A, const ushortT* B, int K) {
        for (int k0 = 0; k0 < K; k0 += 32) {
            stage(A, K, tm * 64, k0, As, 4);
            stage(B, K, tn * BN, k0, Bs, BN / 16);
            __syncthreads();
            short8 af[MT], bf[NT];
            #pragma unroll
            for (int mt = 0; mt < MT; ++mt)
                af[mt] = *(const short8*)(As + (wmo + mt * 16 + (lane & 15)) * 32 + kof);
            #pragma unroll
            for (int nt = 0; nt < NT; ++nt)
                bf[nt] = *(const short8*)(Bs + (wno + nt * 16 + (lane & 15)) * 32 + kof);
            #pragma unroll
            for (int mt = 0; mt < MT; ++mt)
                #pragma unroll
                for (int nt = 0; nt < NT; ++nt)
                    acc[mt][nt] = __builtin_amdgcn_mfma_f32_16x16x32_bf16(
                        af[mt], bf[nt], acc[mt][nt], 0, 0, 0);
            __syncthreads();
        }
    };

    kloop(A1, B1, K1);
    if (B2) kloop(A2, B2, K2);

    const int nb = tn * BN + wno + (lane & 15);
    const int mbl = wmo + ((lane >> 4) << 2);
    #pragma unroll
    for (int nt = 0; nt < NT; ++nt) {
        int n = nb + nt * 16;
        float bv = (EPI == 0) ? 0.f : bias[n];
        #pragma unroll
        for (int mt = 0; mt < MT; ++mt) {
            #pragma unroll
            for (int r = 0; r < 4; ++r) {
                int m = tm * 64 + mbl + mt * 16 + r;
                float v = acc[mt][nt][r] + bv;
                if constexpr (EPI == 0) {
                    int bb = m / 196, tok = m - bb * 196;
                    int reg = n >> 8, head = (n >> 5) & 7, d = n & 31;
                    out[((size_t)((reg * 512 + bb * 8 + head) * 196 + tok)) * 32 + d] = f2b(v);
                } else if constexpr (EPI == 1) {
                    out[(size_t)m * 768 + n] = f2b(v);
                } else if constexpr (EPI == 2) {
                    float gl = 0.5f * v * (1.f + erff(v * 0.70710678118654752f));
                    out[(size_t)m * 1536 + n] = f2b(gl);
                } else {
                    v += b2f(addend[(size_t)m * 768 + n]);
                    int mg = m + m_off;
                    int bb = mg / 196, tok = mg - bb * 196;
                    out[((size_t)(bb * 768 + n)) * 196 + tok] = v;   // fp32 store
                }
            }
        }
    }
}

// ---------------------------------------------------------------- launch
extern "C" void kernel_launch(void* const* d_in, const int* in_sizes, int n_in,
                              void* d_out, int out_size, void* d_ws, size_t ws_size,
                              hipStream_t stream) {
    const float* x       = (const float*)d_in[0];
    const float* W_qkv   = (const float*)d_in[1];
    const float* bias_tb = (const float*)d_in[2];
    const float* W_out   = (const float*)d_in[3];
    const float* b_out   = (const float*)d_in[4];
    const float* ln1_g   = (const float*)d_in[5];
    const float* ln1_b   = (const float*)d_in[6];
    const float* ln2_g   = (const float*)d_in[7];
    const float* ln2_b   = (const float*)d_in[8];
    const float* W_fc1   = (const float*)d_in[9];
    const float* b_fc1   = (const float*)d_in[10];
    const float* W_fc2   = (const float*)d_in[11];
    const float* b_fc2   = (const float*)d_in[12];
    const float* W_proj  = (const float*)d_in[13];
    float* out = (float*)d_out;

    char* ws = (char*)d_ws;
    // compact layout with region reuse; total footprint ~64.1 MB (known-good)
    ushortT* pooled = (ushortT*)(ws);                 // [12544][384]
    ushortT* tln1   = (ushortT*)(ws + 9633792);       // [12544][384]
    ushortT* attno  = tln1;                           // reuse (tln1 dead after qkv gemm)
    ushortT* qkvb   = (ushortT*)(ws + 19267584);      // [3][64][8][196][32]
    ushortT* tln2   = qkvb;                           // reuse (qkvb dead after attn)
    ushortT* mid    = (ushortT*)(ws);                 // [6272][1536] (pooled+tln1 dead by FFN)
    ushortT* htok   = (ushortT*)(ws + 38535168);      // [12544][768]
    ushortT* wTqkv  = (ushortT*)(ws + 57802752);      // [768][384]
    ushortT* wTout  = wTqkv + 768 * 384;              // [768][256]
    ushortT* wTfc1  = wTout + 768 * 256;              // [1536][768]
    ushortT* wTfc2  = wTfc1 + 1536 * 768;             // [768][1536]
    ushortT* wProjB = wTfc2 + 768 * 1536;             // [768][384] (already [N][K])

    // weight transposes ([K,N] fp32 -> [N,K] bf16)
    transpose_k<<<dim3(24, 12), 256, 0, stream>>>(W_qkv, wTqkv, 384, 768);
    transpose_k<<<dim3(24, 8), 256, 0, stream>>>(W_out, wTout, 256, 768);
    transpose_k<<<dim3(48, 24), 256, 0, stream>>>(W_fc1, wTfc1, 768, 1536);
    transpose_k<<<dim3(24, 48), 256, 0, stream>>>(W_fc2, wTfc2, 1536, 768);
    convert_k<<<288, 256, 0, stream>>>(W_proj, wProjB);

    // pool + LN1
    pool_kernel<<<dim3(48, 64), 256, 0, stream>>>(x, pooled);
    ln_kernel<<<M_TOT, 128, 0, stream>>>(pooled, ln1_g, ln1_b, tln1, 384);

    // QKV gemm
    gemm64<128, 0, ushortT><<<dim3(196, 6), 256, 0, stream>>>(tln1, wTqkv, 384,
                                                nullptr, nullptr, 0,
                                                nullptr, nullptr, qkvb, 0);
    attn_kernel<<<512, 256, 0, stream>>>(qkvb, bias_tb, attno);

    // h = attn_out @ W_out^T + pooled @ W_proj^T + b_out
    gemm64<128, 1, ushortT><<<dim3(196, 6), 256, 0, stream>>>(attno, wTout, 256,
                                                pooled, wProjB, 384,
                                                b_out, nullptr, htok, 0);
    ln_kernel<<<M_TOT, 256, 0, stream>>>(htok, ln2_g, ln2_b, tln2, 768);

    // FFN in two M-halves (keeps mid buffer at 19.3 MB)
    for (int half = 0; half < 2; ++half) {
        const ushortT* a2 = tln2 + (size_t)half * M_HALF * 768;
        gemm64<128, 2, ushortT><<<dim3(98, 12), 256, 0, stream>>>(a2, wTfc1, 768,
                                                     nullptr, nullptr, 0,
                                                     b_fc1, nullptr, mid, 0);
        gemm64<64, 3, float><<<dim3(98, 12), 256, 0, stream>>>(mid, wTfc2, 1536,
                                                    nullptr, nullptr, 0,
                                                    b_fc2, htok + (size_t)half * M_HALF * 768,
                                                    out, half * M_HALF);
    }
    (void)in_sizes; (void)n_in; (void)out_size; (void)ws_size;
}

// Round 6
// 487.958 us; speedup vs baseline: 1.1488x; 1.0171x over previous
//
#include <hip/hip_runtime.h>
#include <hip/hip_bf16.h>
#include <cmath>

typedef unsigned short ushortT;
typedef unsigned int u32;
typedef __attribute__((ext_vector_type(8))) short short8;
typedef __attribute__((ext_vector_type(4))) float floatx4;
typedef __attribute__((ext_vector_type(2))) _Float16 half2v;
typedef __attribute__((ext_vector_type(8))) _Float16 half8v;

#define IMG 14
#define NTOK 196          // 14*14
#define BATCH 64
#define M_TOT 12544       // 64*196
#define M_HALF 6272       // 49*128
#define INCH 384
#define OUTCH 768
#define HIDDEN 1536
#define HEADS 8
#define HDIM 32

#if __has_builtin(__builtin_amdgcn_fdot2)
#define FDOT2(a, b, c) __builtin_amdgcn_fdot2((a), (b), (c), false)
#else
#define FDOT2(a, b, c) ((c) + (float)(a)[0] * (float)(b)[0] + (float)(a)[1] * (float)(b)[1])
#endif

__device__ __forceinline__ float b2f(ushortT u) {
    union { u32 i; float f; } v; v.i = ((u32)u) << 16; return v.f;
}
__device__ __forceinline__ ushortT f2b(float f) {
    union { float f; u32 i; } v; v.f = f;
    u32 r = v.i + 0x7FFFu + ((v.i >> 16) & 1u);
    return (ushortT)(r >> 16);
}

__device__ __forceinline__ void async_ld16(const void* g, void* l) {
    __builtin_amdgcn_global_load_lds(
        (const __attribute__((address_space(1))) u32*)g,
        (__attribute__((address_space(3))) u32*)l, 16, 0, 0);
}

// ---------------------------------------------------------------- weight prep (merged)
// blocks [0,288): W_qkv 384x768 transpose; [288,480): W_out 256x768; [480,1632): W_fc1
// 768x1536; [1632,2784): W_fc2 1536x768; [2784,3072): W_proj elementwise convert.
__global__ __launch_bounds__(256) void prep_weights(
    const float* __restrict__ Wqkv, const float* __restrict__ Wout,
    const float* __restrict__ Wfc1, const float* __restrict__ Wfc2,
    const float* __restrict__ Wproj,
    ushortT* __restrict__ oQkv, ushortT* __restrict__ oOut,
    ushortT* __restrict__ oFc1, ushortT* __restrict__ oFc2,
    ushortT* __restrict__ oProj) {
    int blk = blockIdx.x;
    if (blk >= 2784) {   // convert segment (288 blocks x 1024 elems = 294912)
        int i = ((blk - 2784) * 256 + threadIdx.x) * 4;
        float4 v = *(const float4*)(Wproj + i);
        ushortT o[4] = { f2b(v.x), f2b(v.y), f2b(v.z), f2b(v.w) };
        *(uint2*)(oProj + i) = *(const uint2*)o;
        return;
    }
    const float* in; ushortT* out; int R, C, tile;
    if (blk < 288)       { in = Wqkv; out = oQkv; R = 384;  C = 768;  tile = blk; }
    else if (blk < 480)  { in = Wout; out = oOut; R = 256;  C = 768;  tile = blk - 288; }
    else if (blk < 1632) { in = Wfc1; out = oFc1; R = 768;  C = 1536; tile = blk - 480; }
    else                 { in = Wfc2; out = oFc2; R = 1536; C = 768;  tile = blk - 1632; }
    int tilesX = C >> 5;
    int bx = (tile % tilesX) * 32, by = (tile / tilesX) * 32;
    __shared__ ushortT t[32][33];
    int tx = threadIdx.x & 31, ty = threadIdx.x >> 5;
    #pragma unroll
    for (int i = 0; i < 4; ++i) {
        int r = by + ty * 4 + i;
        t[ty * 4 + i][tx] = f2b(in[(size_t)r * C + bx + tx]);
    }
    __syncthreads();
    #pragma unroll
    for (int i = 0; i < 4; ++i) {
        int r = bx + ty * 4 + i;
        out[(size_t)r * R + by + tx] = t[tx][ty * 4 + i];
    }
}

// ---------------------------------------------------------------- maxpool 3x3 s2 p1 (v2)
// x fp32 [64][384][28][28] -> pooled bf16 [12544][384].
// Block = (channel-group of 32, batch). Stage slab as bf16 in LDS (stride 788),
// each thread produces 8 channels x 1 token = 16B store; 4 consecutive threads = 64B line.
#define XSTRIDE 788
__global__ __launch_bounds__(256) void pool_kernel(const float* __restrict__ x,
                                                   ushortT* __restrict__ pooled) {
    int cg = blockIdx.x, b = blockIdx.y;
    int c0 = cg * 32;
    __shared__ ushortT xs[32 * XSTRIDE];
    const float* src = x + ((size_t)b * INCH + c0) * 784;
    for (int i = threadIdx.x; i < 32 * 196; i += 256) {
        int c = i / 196, p4 = (i - c * 196) * 4;
        float4 v = *(const float4*)(src + c * 784 + p4);
        ushortT o[4] = { f2b(v.x), f2b(v.y), f2b(v.z), f2b(v.w) };
        *(uint2*)(xs + c * XSTRIDE + p4) = *(const uint2*)o;
    }
    __syncthreads();
    for (int chunk = threadIdx.x; chunk < NTOK * 4; chunk += 256) {
        int n = chunk >> 2, q = chunk & 3;
        int hh = n / IMG, ww = n - hh * IMG;
        int y0 = hh * 2, x0 = ww * 2;
        int ya = y0 ? y0 - 1 : 0, xa = x0 ? x0 - 1 : 0;
        int yb = y0 + 1, xb = x0 + 1;   // <= 27 always
        ushortT o[8];
        #pragma unroll
        for (int cc = 0; cc < 8; ++cc) {
            const ushortT* base = xs + (q * 8 + cc) * XSTRIDE;
            float mv = -1e30f;
            for (int y = ya; y <= yb; ++y)
                for (int xx = xa; xx <= xb; ++xx)
                    mv = fmaxf(mv, b2f(base[y * 28 + xx]));
            o[cc] = f2b(mv);
        }
        *(uint4*)(pooled + ((size_t)b * NTOK + n) * INCH + c0 + q * 8) = *(const uint4*)o;
    }
}

// ---------------------------------------------------------------- layernorm
__global__ void ln_kernel(const ushortT* __restrict__ in, const float* __restrict__ gw,
                          const float* __restrict__ bw, ushortT* __restrict__ out, int C) {
    int m = blockIdx.x;
    int t = threadIdx.x, B = blockDim.x;
    const ushortT* row = in + (size_t)m * C;
    float v[3];
    #pragma unroll
    for (int i = 0; i < 3; ++i) v[i] = b2f(row[t + i * B]);
    float s = v[0] + v[1] + v[2];
    float q = v[0] * v[0] + v[1] * v[1] + v[2] * v[2];
    #pragma unroll
    for (int off = 32; off > 0; off >>= 1) {
        s += __shfl_down(s, off, 64);
        q += __shfl_down(q, off, 64);
    }
    __shared__ float red[8][2];
    int wv = t >> 6, ln = t & 63, nw = B >> 6;
    if (ln == 0) { red[wv][0] = s; red[wv][1] = q; }
    __syncthreads();
    if (t == 0) {
        float ts = 0.f, tq = 0.f;
        for (int w = 0; w < nw; ++w) { ts += red[w][0]; tq += red[w][1]; }
        red[0][0] = ts; red[0][1] = tq;
    }
    __syncthreads();
    float mu = red[0][0] / (float)C;
    float var = red[0][1] / (float)C - mu * mu;
    float rs = rsqrtf(var + 1e-5f);
    #pragma unroll
    for (int i = 0; i < 3; ++i) {
        int c = t + i * B;
        out[(size_t)m * C + c] = f2b((v[i] - mu) * rs * gw[c] + bw[c]);
    }
}

// ---------------------------------------------------------------- attention (f16 + fdot2, j-pairs)
__global__ __launch_bounds__(256) void attn_kernel(const ushortT* __restrict__ qkv,
                                                   const float* __restrict__ bias_table,
                                                   ushortT* __restrict__ attn_out) {
    int bh = blockIdx.x;
    int b = bh >> 3, h = bh & 7;
    __shared__ _Float16 Kh[NTOK * HDIM];
    __shared__ half2v  Vp[(NTOK / 2) * HDIM];
    const ushortT* kb = qkv + (size_t)(512 + bh) * (NTOK * HDIM);
    const ushortT* vb = qkv + (size_t)(1024 + bh) * (NTOK * HDIM);
    {
        const u32* kb32 = (const u32*)kb;
        half2v* Kh2 = (half2v*)Kh;
        for (int idx = threadIdx.x; idx < NTOK * HDIM / 2; idx += 256) {
            u32 w = kb32[idx];
            half2v p;
            p[0] = (_Float16)b2f((ushortT)(w & 0xFFFFu));
            p[1] = (_Float16)b2f((ushortT)(w >> 16));
            Kh2[idx] = p;
        }
        for (int idx = threadIdx.x; idx < (NTOK / 2) * HDIM; idx += 256) {
            int jp = idx >> 5, d = idx & 31;
            half2v p;
            p[0] = (_Float16)b2f(vb[jp * 64 + d]);
            p[1] = (_Float16)b2f(vb[jp * 64 + 32 + d]);
            Vp[idx] = p;
        }
    }
    __syncthreads();
    int i = threadIdx.x;
    if (i >= NTOK) return;
    const ushortT* qb = qkv + (size_t)bh * (NTOK * HDIM) + i * HDIM;
    half2v qh[16];
    #pragma unroll
    for (int t = 0; t < 16; ++t) {
        qh[t][0] = (_Float16)(b2f(qb[2 * t]) * 0.17677669529663687f);
        qh[t][1] = (_Float16)(b2f(qb[2 * t + 1]) * 0.17677669529663687f);
    }
    int iy = i / IMG, ix = i - iy * IMG;
    int ibase = ((iy + 13) * 27 + (ix + 13)) * 8 + h;
    float O[32];
    #pragma unroll
    for (int d = 0; d < 32; ++d) O[d] = 0.f;
    float l = 0.f;
    int jy = 0, jx = 0;
    union h8 { half8v v8; half2v v2[4]; };
    for (int jp = 0; jp < NTOK / 2; ++jp) {
        const _Float16* k0p = Kh + (2 * jp) * 32;
        float s0 = 0.f, s1 = 0.f;
        #pragma unroll
        for (int c = 0; c < 4; ++c) {
            h8 u0, u1;
            u0.v8 = *(const half8v*)(k0p + c * 8);
            u1.v8 = *(const half8v*)(k0p + 32 + c * 8);
            #pragma unroll
            for (int t = 0; t < 4; ++t) {
                s0 = FDOT2(qh[c * 4 + t], u0.v2[t], s0);
                s1 = FDOT2(qh[c * 4 + t], u1.v2[t], s1);
            }
        }
        float b0 = bias_table[ibase - (jy * 27 + jx) * 8];
        if (++jx == IMG) { jx = 0; ++jy; }
        float b1 = bias_table[ibase - (jy * 27 + jx) * 8];
        if (++jx == IMG) { jx = 0; ++jy; }
        float p0 = __expf(s0 + b0);
        float p1 = __expf(s1 + b1);
        l += p0 + p1;
        half2v pp;
        pp[0] = (_Float16)p0;
        pp[1] = (_Float16)p1;
        const _Float16* vp = (const _Float16*)(Vp + jp * 32);
        #pragma unroll
        for (int c = 0; c < 8; ++c) {
            h8 uv;
            uv.v8 = *(const half8v*)(vp + c * 8);
            #pragma unroll
            for (int t = 0; t < 4; ++t)
                O[c * 4 + t] = FDOT2(pp, uv.v2[t], O[c * 4 + t]);
        }
    }
    float inv = 1.f / l;
    ushortT* dst = attn_out + ((size_t)(b * NTOK + i)) * 256 + h * 32;
    #pragma unroll
    for (int d = 0; d < 32; ++d) dst[d] = f2b(O[d] * inv);
}

// ---------------------------------------------------------------- GEMM BM=64 x BN, BK=32
template <int BN, int EPI, typename OUT_T>
__global__ __launch_bounds__(256) void gemm64(
    const ushortT* __restrict__ A1, const ushortT* __restrict__ B1, int K1,
    const ushortT* __restrict__ A2, const ushortT* __restrict__ B2, int K2,
    const float* __restrict__ bias, const ushortT* __restrict__ addend,
    OUT_T* __restrict__ out, int m_off) {
    __shared__ ushortT As[64 * 32];
    __shared__ ushortT Bs[BN * 32];
    const int tid = threadIdx.x, wave = tid >> 6, lane = tid & 63;
    constexpr int MT = (BN == 128) ? 4 : 2;
    constexpr int NT = 2;
    const int wmo = (BN == 128) ? 0 : (wave & 1) * 32;
    const int wno = (BN == 128) ? wave * 32 : (wave >> 1) * 32;
    const int tm = blockIdx.x, tn = blockIdx.y;

    floatx4 acc[MT][NT];
    #pragma unroll
    for (int a = 0; a < MT; ++a)
        #pragma unroll
        for (int c = 0; c < NT; ++c)
            acc[a][c] = (floatx4){0.f, 0.f, 0.f, 0.f};

    const int glrow = lane >> 2, glcol = (lane & 3) * 8;
    const int kof = (lane >> 4) * 8;

    auto stage = [&](const ushortT* G, int ld, int row0, int k0, ushortT* S, int R16) {
        for (int i = wave; i < R16; i += 4)
            async_ld16(G + (size_t)(row0 + i * 16 + glrow) * ld + k0 + glcol, S + i * 512);
    };

    auto kloop = [&](const ushortT* A, const ushortT* B, int K) {
        for (int k0 = 0; k0 < K; k0 += 32) {
            stage(A, K, tm * 64, k0, As, 4);
            stage(B, K, tn * BN, k0, Bs, BN / 16);
            __syncthreads();
            short8 af[MT], bf[NT];
            #pragma unroll
            for (int mt = 0; mt < MT; ++mt)
                af[mt] = *(const short8*)(As + (wmo + mt * 16 + (lane & 15)) * 32 + kof);
            #pragma unroll
            for (int nt = 0; nt < NT; ++nt)
                bf[nt] = *(const short8*)(Bs + (wno + nt * 16 + (lane & 15)) * 32 + kof);
            #pragma unroll
            for (int mt = 0; mt < MT; ++mt)
                #pragma unroll
                for (int nt = 0; nt < NT; ++nt)
                    acc[mt][nt] = __builtin_amdgcn_mfma_f32_16x16x32_bf16(
                        af[mt], bf[nt], acc[mt][nt], 0, 0, 0);
            __syncthreads();
        }
    };

    kloop(A1, B1, K1);
    if (B2) kloop(A2, B2, K2);

    const int nb = tn * BN + wno + (lane & 15);
    const int mbl = wmo + ((lane >> 4) << 2);
    #pragma unroll
    for (int nt = 0; nt < NT; ++nt) {
        int n = nb + nt * 16;
        float bv = (EPI == 0) ? 0.f : bias[n];
        #pragma unroll
        for (int mt = 0; mt < MT; ++mt) {
            #pragma unroll
            for (int r = 0; r < 4; ++r) {
                int m = tm * 64 + mbl + mt * 16 + r;
                float v = acc[mt][nt][r] + bv;
                if constexpr (EPI == 0) {
                    int bb = m / 196, tok = m - bb * 196;
                    int reg = n >> 8, head = (n >> 5) & 7, d = n & 31;
                    out[((size_t)((reg * 512 + bb * 8 + head) * 196 + tok)) * 32 + d] = f2b(v);
                } else if constexpr (EPI == 1) {
                    out[(size_t)m * 768 + n] = f2b(v);
                } else if constexpr (EPI == 2) {
                    float gl = 0.5f * v * (1.f + erff(v * 0.70710678118654752f));
                    out[(size_t)m * 1536 + n] = f2b(gl);
                } else {
                    v += b2f(addend[(size_t)m * 768 + n]);
                    int mg = m + m_off;
                    int bb = mg / 196, tok = mg - bb * 196;
                    out[((size_t)(bb * 768 + n)) * 196 + tok] = v;   // fp32 store
                }
            }
        }
    }
}

// ---------------------------------------------------------------- launch
extern "C" void kernel_launch(void* const* d_in, const int* in_sizes, int n_in,
                              void* d_out, int out_size, void* d_ws, size_t ws_size,
                              hipStream_t stream) {
    const float* x       = (const float*)d_in[0];
    const float* W_qkv   = (const float*)d_in[1];
    const float* bias_tb = (const float*)d_in[2];
    const float* W_out   = (const float*)d_in[3];
    const float* b_out   = (const float*)d_in[4];
    const float* ln1_g   = (const float*)d_in[5];
    const float* ln1_b   = (const float*)d_in[6];
    const float* ln2_g   = (const float*)d_in[7];
    const float* ln2_b   = (const float*)d_in[8];
    const float* W_fc1   = (const float*)d_in[9];
    const float* b_fc1   = (const float*)d_in[10];
    const float* W_fc2   = (const float*)d_in[11];
    const float* b_fc2   = (const float*)d_in[12];
    const float* W_proj  = (const float*)d_in[13];
    float* out = (float*)d_out;

    char* ws = (char*)d_ws;
    ushortT* pooled = (ushortT*)(ws);                 // [12544][384]
    ushortT* tln1   = (ushortT*)(ws + 9633792);       // [12544][384]
    ushortT* attno  = tln1;                           // reuse
    ushortT* qkvb   = (ushortT*)(ws + 19267584);      // [3][64][8][196][32]
    ushortT* tln2   = qkvb;                           // reuse
    ushortT* mid    = (ushortT*)(ws);                 // [6272][1536] reuse
    ushortT* htok   = (ushortT*)(ws + 38535168);      // [12544][768]
    ushortT* wTqkv  = (ushortT*)(ws + 57802752);      // [768][384]
    ushortT* wTout  = wTqkv + 768 * 384;              // [768][256]
    ushortT* wTfc1  = wTout + 768 * 256;              // [1536][768]
    ushortT* wTfc2  = wTfc1 + 1536 * 768;             // [768][1536]
    ushortT* wProjB = wTfc2 + 768 * 1536;             // [768][384]

    // merged weight prep (4 transposes + 1 convert)
    prep_weights<<<3072, 256, 0, stream>>>(W_qkv, W_out, W_fc1, W_fc2, W_proj,
                                           wTqkv, wTout, wTfc1, wTfc2, wProjB);

    // pool + LN1
    pool_kernel<<<dim3(12, 64), 256, 0, stream>>>(x, pooled);
    ln_kernel<<<M_TOT, 128, 0, stream>>>(pooled, ln1_g, ln1_b, tln1, 384);

    // QKV gemm
    gemm64<128, 0, ushortT><<<dim3(196, 6), 256, 0, stream>>>(tln1, wTqkv, 384,
                                                nullptr, nullptr, 0,
                                                nullptr, nullptr, qkvb, 0);
    attn_kernel<<<512, 256, 0, stream>>>(qkvb, bias_tb, attno);

    // h = attn_out @ W_out^T + pooled @ W_proj^T + b_out
    gemm64<128, 1, ushortT><<<dim3(196, 6), 256, 0, stream>>>(attno, wTout, 256,
                                                pooled, wProjB, 384,
                                                b_out, nullptr, htok, 0);
    ln_kernel<<<M_TOT, 256, 0, stream>>>(htok, ln2_g, ln2_b, tln2, 768);

    // FFN in two M-halves
    for (int half = 0; half < 2; ++half) {
        const ushortT* a2 = tln2 + (size_t)half * M_HALF * 768;
        gemm64<128, 2, ushortT><<<dim3(98, 12), 256, 0, stream>>>(a2, wTfc1, 768,
                                                     nullptr, nullptr, 0,
                                                     b_fc1, nullptr, mid, 0);
        gemm64<64, 3, float><<<dim3(98, 12), 256, 0, stream>>>(mid, wTfc2, 1536,
                                                    nullptr, nullptr, 0,
                                                    b_fc2, htok + (size_t)half * M_HALF * 768,
                                                    out, half * M_HALF);
    }
    (void)in_sizes; (void)n_in; (void)out_size; (void)ws_size;
}

// Round 7
// 467.664 us; speedup vs baseline: 1.1986x; 1.0434x over previous
//
#include <hip/hip_runtime.h>
#include <hip/hip_bf16.h>
#include <cmath>

typedef unsigned short ushortT;
typedef unsigned int u32;
typedef __attribute__((ext_vector_type(8))) short short8;
typedef __attribute__((ext_vector_type(4))) float floatx4;
typedef __attribute__((ext_vector_type(2))) _Float16 half2v;
typedef __attribute__((ext_vector_type(8))) _Float16 half8v;

#define IMG 14
#define NTOK 196          // 14*14
#define BATCH 64
#define M_TOT 12544       // 64*196
#define M_HALF 6272       // 49*128
#define INCH 384
#define OUTCH 768
#define HIDDEN 1536
#define HEADS 8
#define HDIM 32

#if __has_builtin(__builtin_amdgcn_fdot2)
#define FDOT2(a, b, c) __builtin_amdgcn_fdot2((a), (b), (c), false)
#else
#define FDOT2(a, b, c) ((c) + (float)(a)[0] * (float)(b)[0] + (float)(a)[1] * (float)(b)[1])
#endif

__device__ __forceinline__ float b2f(ushortT u) {
    union { u32 i; float f; } v; v.i = ((u32)u) << 16; return v.f;
}
__device__ __forceinline__ ushortT f2b(float f) {
    union { float f; u32 i; } v; v.f = f;
    u32 r = v.i + 0x7FFFu + ((v.i >> 16) & 1u);
    return (ushortT)(r >> 16);
}

__device__ __forceinline__ void async_ld16(const void* g, void* l) {
    __builtin_amdgcn_global_load_lds(
        (const __attribute__((address_space(1))) u32*)g,
        (__attribute__((address_space(3))) u32*)l, 16, 0, 0);
}

// ---------------------------------------------------------------- prep + pool (merged)
// blocks [0,288): W_qkv 384x768 transpose; [288,480): W_out 256x768; [480,1632): W_fc1
// 768x1536; [1632,2784): W_fc2 1536x768; [2784,3072): W_proj convert;
// [3072,4608): maxpool, 16 channels x 1 batch per block, fp32 LDS staged via global_load_lds.
__global__ __launch_bounds__(256) void prep_pool(
    const float* __restrict__ Wqkv, const float* __restrict__ Wout,
    const float* __restrict__ Wfc1, const float* __restrict__ Wfc2,
    const float* __restrict__ Wproj, const float* __restrict__ x,
    ushortT* __restrict__ oQkv, ushortT* __restrict__ oOut,
    ushortT* __restrict__ oFc1, ushortT* __restrict__ oFc2,
    ushortT* __restrict__ oProj, ushortT* __restrict__ pooled) {
    __shared__ __align__(16) char lds_raw[50176];
    int blk = blockIdx.x;
    int tid = threadIdx.x;
    if (blk >= 3072) {
        // ---------------- maxpool ----------------
        int pblk = blk - 3072;
        int cg = pblk % 24, b = pblk / 24;
        float* xs = (float*)lds_raw;                       // [16][784] fp32
        const char* src = (const char*)(x + ((size_t)b * INCH + cg * 16) * 784);
        int wave = tid >> 6, lane = tid & 63;
        for (int j = wave; j < 49; j += 4)
            async_ld16(src + j * 1024 + lane * 16, lds_raw + j * 1024);
        __syncthreads();
        for (int chunk = tid; chunk < NTOK * 2; chunk += 256) {
            int n = chunk >> 1, q = chunk & 1;
            int hh = n / IMG, ww = n - hh * IMG;
            int y0 = hh * 2, x0 = ww * 2;
            int ya = y0 ? y0 - 1 : 0, xa = x0 ? x0 - 1 : 0;
            int yb = y0 + 1, xb = x0 + 1;   // <= 27 always
            ushortT o[8];
            #pragma unroll
            for (int cc = 0; cc < 8; ++cc) {
                const float* base = xs + (q * 8 + cc) * 784;
                float mv = -1e30f;
                for (int y = ya; y <= yb; ++y)
                    for (int xx = xa; xx <= xb; ++xx)
                        mv = fmaxf(mv, base[y * 28 + xx]);
                o[cc] = f2b(mv);
            }
            *(uint4*)(pooled + ((size_t)b * NTOK + n) * INCH + cg * 16 + q * 8) =
                *(const uint4*)o;
        }
        return;
    }
    if (blk >= 2784) {   // convert segment (288 blocks x 1024 elems)
        int i = ((blk - 2784) * 256 + tid) * 4;
        float4 v = *(const float4*)(Wproj + i);
        ushortT o[4] = { f2b(v.x), f2b(v.y), f2b(v.z), f2b(v.w) };
        *(uint2*)(oProj + i) = *(const uint2*)o;
        return;
    }
    const float* in; ushortT* out; int R, C, tile;
    if (blk < 288)       { in = Wqkv; out = oQkv; R = 384;  C = 768;  tile = blk; }
    else if (blk < 480)  { in = Wout; out = oOut; R = 256;  C = 768;  tile = blk - 288; }
    else if (blk < 1632) { in = Wfc1; out = oFc1; R = 768;  C = 1536; tile = blk - 480; }
    else                 { in = Wfc2; out = oFc2; R = 1536; C = 768;  tile = blk - 1632; }
    int tilesX = C >> 5;
    int bx = (tile % tilesX) * 32, by = (tile / tilesX) * 32;
    ushortT (*t)[33] = (ushortT (*)[33])lds_raw;
    int tx = tid & 31, ty = tid >> 5;
    #pragma unroll
    for (int i = 0; i < 4; ++i) {
        int r = by + ty * 4 + i;
        t[ty * 4 + i][tx] = f2b(in[(size_t)r * C + bx + tx]);
    }
    __syncthreads();
    #pragma unroll
    for (int i = 0; i < 4; ++i) {
        int r = bx + ty * 4 + i;
        out[(size_t)r * R + by + tx] = t[tx][ty * 4 + i];
    }
}

// ---------------------------------------------------------------- layernorm (wave-per-row)
// C = 192*VE (VE=2 -> 384, VE=4 -> 768). Block 256 = 4 rows, grid M/4. No LDS, no barriers.
template <int VE>
__global__ __launch_bounds__(256) void ln_kernel(const ushortT* __restrict__ in,
                                                 const float* __restrict__ gw,
                                                 const float* __restrict__ bw,
                                                 ushortT* __restrict__ out) {
    constexpr int C = 192 * VE;
    int wave = threadIdx.x >> 6, lane = threadIdx.x & 63;
    int m = blockIdx.x * 4 + wave;
    const ushortT* row = in + (size_t)m * C;
    float v[3][VE];
    float s = 0.f, q = 0.f;
    #pragma unroll
    for (int seg = 0; seg < 3; ++seg) {
        int idx = seg * 64 * VE + lane * VE;
        ushortT tmp[VE];
        if constexpr (VE == 2) *(u32*)tmp = *(const u32*)(row + idx);
        else                   *(uint2*)tmp = *(const uint2*)(row + idx);
        #pragma unroll
        for (int k = 0; k < VE; ++k) {
            float f = b2f(tmp[k]);
            v[seg][k] = f;
            s += f;
            q += f * f;
        }
    }
    #pragma unroll
    for (int off = 32; off > 0; off >>= 1) {
        s += __shfl_xor(s, off, 64);
        q += __shfl_xor(q, off, 64);
    }
    float mu = s / (float)C;
    float var = q / (float)C - mu * mu;
    float rs = rsqrtf(var + 1e-5f);
    #pragma unroll
    for (int seg = 0; seg < 3; ++seg) {
        int idx = seg * 64 * VE + lane * VE;
        float g[VE], bb[VE];
        if constexpr (VE == 2) {
            *(float2*)g = *(const float2*)(gw + idx);
            *(float2*)bb = *(const float2*)(bw + idx);
        } else {
            *(float4*)g = *(const float4*)(gw + idx);
            *(float4*)bb = *(const float4*)(bw + idx);
        }
        ushortT o[VE];
        #pragma unroll
        for (int k = 0; k < VE; ++k)
            o[k] = f2b((v[seg][k] - mu) * rs * g[k] + bb[k]);
        if constexpr (VE == 2) *(u32*)(out + (size_t)m * C + idx) = *(const u32*)o;
        else                   *(uint2*)(out + (size_t)m * C + idx) = *(const uint2*)o;
    }
}

// ---------------------------------------------------------------- attention (f16 + fdot2, j-pairs)
__global__ __launch_bounds__(256) void attn_kernel(const ushortT* __restrict__ qkv,
                                                   const float* __restrict__ bias_table,
                                                   ushortT* __restrict__ attn_out) {
    int bh = blockIdx.x;
    int b = bh >> 3, h = bh & 7;
    __shared__ _Float16 Kh[NTOK * HDIM];
    __shared__ half2v  Vp[(NTOK / 2) * HDIM];
    const ushortT* kb = qkv + (size_t)(512 + bh) * (NTOK * HDIM);
    const ushortT* vb = qkv + (size_t)(1024 + bh) * (NTOK * HDIM);
    {
        const u32* kb32 = (const u32*)kb;
        half2v* Kh2 = (half2v*)Kh;
        for (int idx = threadIdx.x; idx < NTOK * HDIM / 2; idx += 256) {
            u32 w = kb32[idx];
            half2v p;
            p[0] = (_Float16)b2f((ushortT)(w & 0xFFFFu));
            p[1] = (_Float16)b2f((ushortT)(w >> 16));
            Kh2[idx] = p;
        }
        for (int idx = threadIdx.x; idx < (NTOK / 2) * HDIM; idx += 256) {
            int jp = idx >> 5, d = idx & 31;
            half2v p;
            p[0] = (_Float16)b2f(vb[jp * 64 + d]);
            p[1] = (_Float16)b2f(vb[jp * 64 + 32 + d]);
            Vp[idx] = p;
        }
    }
    __syncthreads();
    int i = threadIdx.x;
    if (i >= NTOK) return;
    const ushortT* qb = qkv + (size_t)bh * (NTOK * HDIM) + i * HDIM;
    half2v qh[16];
    #pragma unroll
    for (int t = 0; t < 16; ++t) {
        qh[t][0] = (_Float16)(b2f(qb[2 * t]) * 0.17677669529663687f);
        qh[t][1] = (_Float16)(b2f(qb[2 * t + 1]) * 0.17677669529663687f);
    }
    int iy = i / IMG, ix = i - iy * IMG;
    int ibase = ((iy + 13) * 27 + (ix + 13)) * 8 + h;
    float O[32];
    #pragma unroll
    for (int d = 0; d < 32; ++d) O[d] = 0.f;
    float l = 0.f;
    int jy = 0, jx = 0;
    union h8 { half8v v8; half2v v2[4]; };
    for (int jp = 0; jp < NTOK / 2; ++jp) {
        const _Float16* k0p = Kh + (2 * jp) * 32;
        float s0 = 0.f, s1 = 0.f;
        #pragma unroll
        for (int c = 0; c < 4; ++c) {
            h8 u0, u1;
            u0.v8 = *(const half8v*)(k0p + c * 8);
            u1.v8 = *(const half8v*)(k0p + 32 + c * 8);
            #pragma unroll
            for (int t = 0; t < 4; ++t) {
                s0 = FDOT2(qh[c * 4 + t], u0.v2[t], s0);
                s1 = FDOT2(qh[c * 4 + t], u1.v2[t], s1);
            }
        }
        float b0 = bias_table[ibase - (jy * 27 + jx) * 8];
        if (++jx == IMG) { jx = 0; ++jy; }
        float b1 = bias_table[ibase - (jy * 27 + jx) * 8];
        if (++jx == IMG) { jx = 0; ++jy; }
        float p0 = __expf(s0 + b0);
        float p1 = __expf(s1 + b1);
        l += p0 + p1;
        half2v pp;
        pp[0] = (_Float16)p0;
        pp[1] = (_Float16)p1;
        const _Float16* vp = (const _Float16*)(Vp + jp * 32);
        #pragma unroll
        for (int c = 0; c < 8; ++c) {
            h8 uv;
            uv.v8 = *(const half8v*)(vp + c * 8);
            #pragma unroll
            for (int t = 0; t < 4; ++t)
                O[c * 4 + t] = FDOT2(pp, uv.v2[t], O[c * 4 + t]);
        }
    }
    float inv = 1.f / l;
    ushortT* dst = attn_out + ((size_t)(b * NTOK + i)) * 256 + h * 32;
    #pragma unroll
    for (int d = 0; d < 32; ++d) dst[d] = f2b(O[d] * inv);
}

// ---------------------------------------------------------------- GEMM BM=64 x BN, BK=32
template <int BN, int EPI, typename OUT_T>
__global__ __launch_bounds__(256) void gemm64(
    const ushortT* __restrict__ A1, const ushortT* __restrict__ B1, int K1,
    const ushortT* __restrict__ A2, const ushortT* __restrict__ B2, int K2,
    const float* __restrict__ bias, const ushortT* __restrict__ addend,
    OUT_T* __restrict__ out, int m_off) {
    __shared__ ushortT As[64 * 32];
    __shared__ ushortT Bs[BN * 32];
    const int tid = threadIdx.x, wave = tid >> 6, lane = tid & 63;
    constexpr int MT = (BN == 128) ? 4 : 2;
    constexpr int NT = 2;
    const int wmo = (BN == 128) ? 0 : (wave & 1) * 32;
    const int wno = (BN == 128) ? wave * 32 : (wave >> 1) * 32;
    const int tm = blockIdx.x, tn = blockIdx.y;

    floatx4 acc[MT][NT];
    #pragma unroll
    for (int a = 0; a < MT; ++a)
        #pragma unroll
        for (int c = 0; c < NT; ++c)
            acc[a][c] = (floatx4){0.f, 0.f, 0.f, 0.f};

    const int glrow = lane >> 2, glcol = (lane & 3) * 8;
    const int kof = (lane >> 4) * 8;

    auto stage = [&](const ushortT* G, int ld, int row0, int k0, ushortT* S, int R16) {
        for (int i = wave; i < R16; i += 4)
            async_ld16(G + (size_t)(row0 + i * 16 + glrow) * ld + k0 + glcol, S + i * 512);
    };

    auto kloop = [&](const ushortT* A, const ushortT* B, int K) {
        for (int k0 = 0; k0 < K; k0 += 32) {
            stage(A, K, tm * 64, k0, As, 4);
            stage(B, K, tn * BN, k0, Bs, BN / 16);
            __syncthreads();
            short8 af[MT], bf[NT];
            #pragma unroll
            for (int mt = 0; mt < MT; ++mt)
                af[mt] = *(const short8*)(As + (wmo + mt * 16 + (lane & 15)) * 32 + kof);
            #pragma unroll
            for (int nt = 0; nt < NT; ++nt)
                bf[nt] = *(const short8*)(Bs + (wno + nt * 16 + (lane & 15)) * 32 + kof);
            #pragma unroll
            for (int mt = 0; mt < MT; ++mt)
                #pragma unroll
                for (int nt = 0; nt < NT; ++nt)
                    acc[mt][nt] = __builtin_amdgcn_mfma_f32_16x16x32_bf16(
                        af[mt], bf[nt], acc[mt][nt], 0, 0, 0);
            __syncthreads();
        }
    };

    kloop(A1, B1, K1);
    if (B2) kloop(A2, B2, K2);

    const int nb = tn * BN + wno + (lane & 15);
    const int mbl = wmo + ((lane >> 4) << 2);
    #pragma unroll
    for (int nt = 0; nt < NT; ++nt) {
        int n = nb + nt * 16;
        float bv = (EPI == 0) ? 0.f : bias[n];
        #pragma unroll
        for (int mt = 0; mt < MT; ++mt) {
            #pragma unroll
            for (int r = 0; r < 4; ++r) {
                int m = tm * 64 + mbl + mt * 16 + r;
                float v = acc[mt][nt][r] + bv;
                if constexpr (EPI == 0) {
                    int bb = m / 196, tok = m - bb * 196;
                    int reg = n >> 8, head = (n >> 5) & 7, d = n & 31;
                    out[((size_t)((reg * 512 + bb * 8 + head) * 196 + tok)) * 32 + d] = f2b(v);
                } else if constexpr (EPI == 1) {
                    out[(size_t)m * 768 + n] = f2b(v);
                } else if constexpr (EPI == 2) {
                    float gl = 0.5f * v * (1.f + erff(v * 0.70710678118654752f));
                    out[(size_t)m * 1536 + n] = f2b(gl);
                } else {
                    v += b2f(addend[(size_t)m * 768 + n]);
                    int mg = m + m_off;
                    int bb = mg / 196, tok = mg - bb * 196;
                    out[((size_t)(bb * 768 + n)) * 196 + tok] = v;   // fp32 store
                }
            }
        }
    }
}

// ---------------------------------------------------------------- launch
extern "C" void kernel_launch(void* const* d_in, const int* in_sizes, int n_in,
                              void* d_out, int out_size, void* d_ws, size_t ws_size,
                              hipStream_t stream) {
    const float* x       = (const float*)d_in[0];
    const float* W_qkv   = (const float*)d_in[1];
    const float* bias_tb = (const float*)d_in[2];
    const float* W_out   = (const float*)d_in[3];
    const float* b_out   = (const float*)d_in[4];
    const float* ln1_g   = (const float*)d_in[5];
    const float* ln1_b   = (const float*)d_in[6];
    const float* ln2_g   = (const float*)d_in[7];
    const float* ln2_b   = (const float*)d_in[8];
    const float* W_fc1   = (const float*)d_in[9];
    const float* b_fc1   = (const float*)d_in[10];
    const float* W_fc2   = (const float*)d_in[11];
    const float* b_fc2   = (const float*)d_in[12];
    const float* W_proj  = (const float*)d_in[13];
    float* out = (float*)d_out;

    char* ws = (char*)d_ws;
    ushortT* pooled = (ushortT*)(ws);                 // [12544][384]
    ushortT* tln1   = (ushortT*)(ws + 9633792);       // [12544][384]
    ushortT* attno  = tln1;                           // reuse
    ushortT* qkvb   = (ushortT*)(ws + 19267584);      // [3][64][8][196][32]
    ushortT* tln2   = qkvb;                           // reuse
    ushortT* mid    = (ushortT*)(ws);                 // [6272][1536] reuse
    ushortT* htok   = (ushortT*)(ws + 38535168);      // [12544][768]
    ushortT* wTqkv  = (ushortT*)(ws + 57802752);      // [768][384]
    ushortT* wTout  = wTqkv + 768 * 384;              // [768][256]
    ushortT* wTfc1  = wTout + 768 * 256;              // [1536][768]
    ushortT* wTfc2  = wTfc1 + 1536 * 768;             // [768][1536]
    ushortT* wProjB = wTfc2 + 768 * 1536;             // [768][384]

    // merged weight prep + pool
    prep_pool<<<4608, 256, 0, stream>>>(W_qkv, W_out, W_fc1, W_fc2, W_proj, x,
                                        wTqkv, wTout, wTfc1, wTfc2, wProjB, pooled);

    // LN1
    ln_kernel<2><<<M_TOT / 4, 256, 0, stream>>>(pooled, ln1_g, ln1_b, tln1);

    // QKV gemm
    gemm64<128, 0, ushortT><<<dim3(196, 6), 256, 0, stream>>>(tln1, wTqkv, 384,
                                                nullptr, nullptr, 0,
                                                nullptr, nullptr, qkvb, 0);
    attn_kernel<<<512, 256, 0, stream>>>(qkvb, bias_tb, attno);

    // h = attn_out @ W_out^T + pooled @ W_proj^T + b_out
    gemm64<128, 1, ushortT><<<dim3(196, 6), 256, 0, stream>>>(attno, wTout, 256,
                                                pooled, wProjB, 384,
                                                b_out, nullptr, htok, 0);
    // LN2
    ln_kernel<4><<<M_TOT / 4, 256, 0, stream>>>(htok, ln2_g, ln2_b, tln2);

    // FFN in two M-halves
    for (int half = 0; half < 2; ++half) {
        const ushortT* a2 = tln2 + (size_t)half * M_HALF * 768;
        gemm64<128, 2, ushortT><<<dim3(98, 12), 256, 0, stream>>>(a2, wTfc1, 768,
                                                     nullptr, nullptr, 0,
                                                     b_fc1, nullptr, mid, 0);
        gemm64<64, 3, float><<<dim3(98, 12), 256, 0, stream>>>(mid, wTfc2, 1536,
                                                    nullptr, nullptr, 0,
                                                    b_fc2, htok + (size_t)half * M_HALF * 768,
                                                    out, half * M_HALF);
    }
    (void)in_sizes; (void)n_in; (void)out_size; (void)ws_size;
}

// Round 8
// 426.829 us; speedup vs baseline: 1.3133x; 1.0957x over previous
//
#include <hip/hip_runtime.h>
#include <hip/hip_bf16.h>
#include <cmath>

typedef unsigned short ushortT;
typedef unsigned int u32;
typedef __attribute__((ext_vector_type(8))) short short8;
typedef __attribute__((ext_vector_type(4))) float floatx4;

#define IMG 14
#define NTOK 196          // 14*14
#define BATCH 64
#define M_TOT 12544       // 64*196
#define M_HALF 6272       // 49*128
#define INCH 384
#define OUTCH 768
#define HIDDEN 1536
#define HEADS 8
#define HDIM 32
#define SCALE 0.17677669529663687f

__device__ __forceinline__ float b2f(ushortT u) {
    union { u32 i; float f; } v; v.i = ((u32)u) << 16; return v.f;
}
__device__ __forceinline__ ushortT f2b(float f) {
    union { float f; u32 i; } v; v.f = f;
    u32 r = v.i + 0x7FFFu + ((v.i >> 16) & 1u);
    return (ushortT)(r >> 16);
}

__device__ __forceinline__ void async_ld16(const void* g, void* l) {
    __builtin_amdgcn_global_load_lds(
        (const __attribute__((address_space(1))) u32*)g,
        (__attribute__((address_space(3))) u32*)l, 16, 0, 0);
}

// ---------------------------------------------------------------- prep + pool + bias-expand
// blocks [0,288): W_qkv 384x768 transpose; [288,480): W_out 256x768; [480,1632): W_fc1;
// [1632,2784): W_fc2; [2784,3072): W_proj convert; [3072,4608): maxpool;
// [4608,4946): bias_exp[8][208][208] fp32 expansion.
__global__ __launch_bounds__(256) void prep_pool(
    const float* __restrict__ Wqkv, const float* __restrict__ Wout,
    const float* __restrict__ Wfc1, const float* __restrict__ Wfc2,
    const float* __restrict__ Wproj, const float* __restrict__ x,
    const float* __restrict__ bias_tb,
    ushortT* __restrict__ oQkv, ushortT* __restrict__ oOut,
    ushortT* __restrict__ oFc1, ushortT* __restrict__ oFc2,
    ushortT* __restrict__ oProj, ushortT* __restrict__ pooled,
    float* __restrict__ bias_exp) {
    __shared__ __align__(16) char lds_raw[50176];
    int blk = blockIdx.x;
    int tid = threadIdx.x;
    if (blk >= 4608) {
        // ---------------- bias expansion: [8][208][208] fp32 ----------------
        int idx4 = (blk - 4608) * 256 + tid;          // 0..86527 (exact)
        int h = idx4 / 10816;                          // 208*208/4
        int rem = idx4 - h * 10816;
        int i = rem / 52;
        int j0 = (rem - i * 52) * 4;
        float v[4];
        #pragma unroll
        for (int u = 0; u < 4; ++u) {
            int j = j0 + u;
            float val = 0.f;
            if (i < 196 && j < 196) {
                int iy = i / 14, ix = i - iy * 14;
                int jy = j / 14, jx = j - jy * 14;
                val = bias_tb[((iy - jy + 13) * 27 + (ix - jx + 13)) * 8 + h];
            }
            v[u] = val;
        }
        *(float4*)(bias_exp + (size_t)idx4 * 4) = *(const float4*)v;
        return;
    }
    if (blk >= 3072) {
        // ---------------- maxpool ----------------
        int pblk = blk - 3072;
        int cg = pblk % 24, b = pblk / 24;
        float* xs = (float*)lds_raw;                       // [16][784] fp32
        const char* src = (const char*)(x + ((size_t)b * INCH + cg * 16) * 784);
        int wave = tid >> 6, lane = tid & 63;
        for (int j = wave; j < 49; j += 4)
            async_ld16(src + j * 1024 + lane * 16, lds_raw + j * 1024);
        __syncthreads();
        for (int chunk = tid; chunk < NTOK * 2; chunk += 256) {
            int n = chunk >> 1, q = chunk & 1;
            int hh = n / IMG, ww = n - hh * IMG;
            int y0 = hh * 2, x0 = ww * 2;
            int ya = y0 ? y0 - 1 : 0, xa = x0 ? x0 - 1 : 0;
            int yb = y0 + 1, xb = x0 + 1;   // <= 27 always
            ushortT o[8];
            #pragma unroll
            for (int cc = 0; cc < 8; ++cc) {
                const float* base = xs + (q * 8 + cc) * 784;
                float mv = -1e30f;
                for (int y = ya; y <= yb; ++y)
                    for (int xx = xa; xx <= xb; ++xx)
                        mv = fmaxf(mv, base[y * 28 + xx]);
                o[cc] = f2b(mv);
            }
            *(uint4*)(pooled + ((size_t)b * NTOK + n) * INCH + cg * 16 + q * 8) =
                *(const uint4*)o;
        }
        return;
    }
    if (blk >= 2784) {   // convert segment (288 blocks x 1024 elems)
        int i = ((blk - 2784) * 256 + tid) * 4;
        float4 v = *(const float4*)(Wproj + i);
        ushortT o[4] = { f2b(v.x), f2b(v.y), f2b(v.z), f2b(v.w) };
        *(uint2*)(oProj + i) = *(const uint2*)o;
        return;
    }
    const float* in; ushortT* out; int R, C, tile;
    if (blk < 288)       { in = Wqkv; out = oQkv; R = 384;  C = 768;  tile = blk; }
    else if (blk < 480)  { in = Wout; out = oOut; R = 256;  C = 768;  tile = blk - 288; }
    else if (blk < 1632) { in = Wfc1; out = oFc1; R = 768;  C = 1536; tile = blk - 480; }
    else                 { in = Wfc2; out = oFc2; R = 1536; C = 768;  tile = blk - 1632; }
    int tilesX = C >> 5;
    int bx = (tile % tilesX) * 32, by = (tile / tilesX) * 32;
    ushortT (*t)[33] = (ushortT (*)[33])lds_raw;
    int tx = tid & 31, ty = tid >> 5;
    #pragma unroll
    for (int i = 0; i < 4; ++i) {
        int r = by + ty * 4 + i;
        t[ty * 4 + i][tx] = f2b(in[(size_t)r * C + bx + tx]);
    }
    __syncthreads();
    #pragma unroll
    for (int i = 0; i < 4; ++i) {
        int r = bx + ty * 4 + i;
        out[(size_t)r * R + by + tx] = t[tx][ty * 4 + i];
    }
}

// ---------------------------------------------------------------- layernorm (wave-per-row)
template <int VE>
__global__ __launch_bounds__(256) void ln_kernel(const ushortT* __restrict__ in,
                                                 const float* __restrict__ gw,
                                                 const float* __restrict__ bw,
                                                 ushortT* __restrict__ out) {
    constexpr int C = 192 * VE;
    int wave = threadIdx.x >> 6, lane = threadIdx.x & 63;
    int m = blockIdx.x * 4 + wave;
    const ushortT* row = in + (size_t)m * C;
    float v[3][VE];
    float s = 0.f, q = 0.f;
    #pragma unroll
    for (int seg = 0; seg < 3; ++seg) {
        int idx = seg * 64 * VE + lane * VE;
        ushortT tmp[VE];
        if constexpr (VE == 2) *(u32*)tmp = *(const u32*)(row + idx);
        else                   *(uint2*)tmp = *(const uint2*)(row + idx);
        #pragma unroll
        for (int k = 0; k < VE; ++k) {
            float f = b2f(tmp[k]);
            v[seg][k] = f;
            s += f;
            q += f * f;
        }
    }
    #pragma unroll
    for (int off = 32; off > 0; off >>= 1) {
        s += __shfl_xor(s, off, 64);
        q += __shfl_xor(q, off, 64);
    }
    float mu = s / (float)C;
    float var = q / (float)C - mu * mu;
    float rs = rsqrtf(var + 1e-5f);
    #pragma unroll
    for (int seg = 0; seg < 3; ++seg) {
        int idx = seg * 64 * VE + lane * VE;
        float g[VE], bb[VE];
        if constexpr (VE == 2) {
            *(float2*)g = *(const float2*)(gw + idx);
            *(float2*)bb = *(const float2*)(bw + idx);
        } else {
            *(float4*)g = *(const float4*)(gw + idx);
            *(float4*)bb = *(const float4*)(bw + idx);
        }
        ushortT o[VE];
        #pragma unroll
        for (int k = 0; k < VE; ++k)
            o[k] = f2b((v[seg][k] - mu) * rs * g[k] + bb[k]);
        if constexpr (VE == 2) *(u32*)(out + (size_t)m * C + idx) = *(const u32*)o;
        else                   *(uint2*)(out + (size_t)m * C + idx) = *(const uint2*)o;
    }
}

// ---------------------------------------------------------------- MFMA attention
// qkv bf16 [3][64][8][196][32]; bias_exp fp32 [8][208][208]; one block per (b,h), 4 waves.
// QK^T and PV via 16x16x32 bf16 MFMA; P round-trips LDS (C-layout -> A-layout).
__global__ __launch_bounds__(256) void attn_kernel(const ushortT* __restrict__ qkv,
                                                   const float* __restrict__ bias_exp,
                                                   ushortT* __restrict__ attn_out) {
    int bh = blockIdx.x;
    int b = bh >> 3, h = bh & 7;
    __shared__ ushortT Qs[208 * 32];
    __shared__ ushortT Ks[208 * 32];
    __shared__ ushortT Vts[32 * 232];       // V^T, row stride 232 (16B aligned)
    __shared__ ushortT Ps[4][16 * 232];     // per-wave P strip
    const int tid = threadIdx.x, wave = tid >> 6, lane = tid & 63;

    const uint4* q4 = (const uint4*)(qkv + (size_t)bh * 6272);
    const uint4* k4 = (const uint4*)(qkv + (size_t)(512 + bh) * 6272);
    const uint4* v4 = (const uint4*)(qkv + (size_t)(1024 + bh) * 6272);
    uint4* Q4 = (uint4*)Qs;
    uint4* K4 = (uint4*)Ks;
    for (int t = tid; t < 784; t += 256) { Q4[t] = q4[t]; K4[t] = k4[t]; }
    const uint4 z4 = {0, 0, 0, 0};
    for (int t = tid; t < 48; t += 256) { Q4[784 + t] = z4; K4[784 + t] = z4; }
    // V transpose into Vts
    for (int t = tid; t < 784; t += 256) {
        int j = t >> 2, d0 = (t & 3) * 8;
        uint4 v = v4[t];
        const ushortT* vs = (const ushortT*)&v;
        #pragma unroll
        for (int u = 0; u < 8; ++u)
            Vts[(d0 + u) * 232 + j] = vs[u];
    }
    for (int t = tid; t < 1152; t += 256) {           // zero Vts cols 196..231
        int d = t / 36, j = 196 + t - d * 36;
        Vts[d * 232 + j] = 0;
    }
    for (int t = tid; t < 1536; t += 256) {           // zero Ps cols 208..231
        int w = t / 384, rem = t - w * 384;
        int row = rem / 24, j = 208 + rem - (rem / 24) * 24;
        Ps[w][row * 232 + j] = 0;
    }
    __syncthreads();

    // cache all 13 K B-fragments
    const int fr = (lane & 15), fk = (lane >> 4) * 8;
    short8 kf[13];
    #pragma unroll
    for (int nt = 0; nt < 13; ++nt)
        kf[nt] = *(const short8*)(Ks + (nt * 16 + fr) * 32 + fk);

    const int i0r = (lane >> 4) * 4;   // C-layout row base
    const int colL = lane & 15;        // C-layout col
    ushortT* Pw = &Ps[wave][0];

    for (int mt = wave; mt < 13; mt += 4) {
        short8 af = *(const short8*)(Qs + (mt * 16 + fr) * 32 + fk);
        floatx4 sc[13];
        #pragma unroll
        for (int nt = 0; nt < 13; ++nt)
            sc[nt] = __builtin_amdgcn_mfma_f32_16x16x32_bf16(
                af, kf[nt], (floatx4){0.f, 0.f, 0.f, 0.f}, 0, 0, 0);

        float rsum[4] = {0.f, 0.f, 0.f, 0.f};
        const float* bb = bias_exp + ((size_t)h * 208 + mt * 16 + i0r) * 208 + colL;
        #pragma unroll
        for (int nt = 0; nt < 13; ++nt) {
            #pragma unroll
            for (int r = 0; r < 4; ++r) {
                float bias = bb[r * 208 + nt * 16];
                float p = __expf(sc[nt][r] * SCALE + bias);
                if (nt == 12 && colL >= 4) p = 0.f;   // mask j >= 196
                rsum[r] += p;
                Pw[(i0r + r) * 232 + nt * 16 + colL] = f2b(p);
            }
        }
        #pragma unroll
        for (int off = 1; off < 16; off <<= 1) {
            #pragma unroll
            for (int r = 0; r < 4; ++r) rsum[r] += __shfl_xor(rsum[r], off, 64);
        }

        floatx4 o[2];
        o[0] = (floatx4){0.f, 0.f, 0.f, 0.f};
        o[1] = (floatx4){0.f, 0.f, 0.f, 0.f};
        #pragma unroll
        for (int kt = 0; kt < 7; ++kt) {
            short8 pf = *(const short8*)(Pw + fr * 232 + kt * 32 + fk);
            #pragma unroll
            for (int n2 = 0; n2 < 2; ++n2) {
                short8 vf = *(const short8*)(Vts + (n2 * 16 + fr) * 232 + kt * 32 + fk);
                o[n2] = __builtin_amdgcn_mfma_f32_16x16x32_bf16(pf, vf, o[n2], 0, 0, 0);
            }
        }
        float invl[4];
        #pragma unroll
        for (int r = 0; r < 4; ++r) invl[r] = 1.f / rsum[r];
        #pragma unroll
        for (int n2 = 0; n2 < 2; ++n2) {
            #pragma unroll
            for (int r = 0; r < 4; ++r) {
                int i = mt * 16 + i0r + r;
                if (i < 196)
                    attn_out[((size_t)(b * 196 + i)) * 256 + h * 32 + n2 * 16 + colL] =
                        f2b(o[n2][r] * invl[r]);
            }
        }
    }
}

// ---------------------------------------------------------------- GEMM BM=64 x BN, BK=32
template <int BN, int EPI, typename OUT_T>
__global__ __launch_bounds__(256) void gemm64(
    const ushortT* __restrict__ A1, const ushortT* __restrict__ B1, int K1,
    const ushortT* __restrict__ A2, const ushortT* __restrict__ B2, int K2,
    const float* __restrict__ bias, const ushortT* __restrict__ addend,
    OUT_T* __restrict__ out, int m_off) {
    __shared__ ushortT As[64 * 32];
    __shared__ ushortT Bs[BN * 32];
    const int tid = threadIdx.x, wave = tid >> 6, lane = tid & 63;
    constexpr int MT = (BN == 128) ? 4 : 2;
    constexpr int NT = 2;
    const int wmo = (BN == 128) ? 0 : (wave & 1) * 32;
    const int wno = (BN == 128) ? wave * 32 : (wave >> 1) * 32;
    const int tm = blockIdx.x, tn = blockIdx.y;

    floatx4 acc[MT][NT];
    #pragma unroll
    for (int a = 0; a < MT; ++a)
        #pragma unroll
        for (int c = 0; c < NT; ++c)
            acc[a][c] = (floatx4){0.f, 0.f, 0.f, 0.f};

    const int glrow = lane >> 2, glcol = (lane & 3) * 8;
    const int kof = (lane >> 4) * 8;

    auto stage = [&](const ushortT* G, int ld, int row0, int k0, ushortT* S, int R16) {
        for (int i = wave; i < R16; i += 4)
            async_ld16(G + (size_t)(row0 + i * 16 + glrow) * ld + k0 + glcol, S + i * 512);
    };

    auto kloop = [&](const ushortT* A, const ushortT* B, int K) {
        for (int k0 = 0; k0 < K; k0 += 32) {
            stage(A, K, tm * 64, k0, As, 4);
            stage(B, K, tn * BN, k0, Bs, BN / 16);
            __syncthreads();
            short8 af[MT], bf[NT];
            #pragma unroll
            for (int mt = 0; mt < MT; ++mt)
                af[mt] = *(const short8*)(As + (wmo + mt * 16 + (lane & 15)) * 32 + kof);
            #pragma unroll
            for (int nt = 0; nt < NT; ++nt)
                bf[nt] = *(const short8*)(Bs + (wno + nt * 16 + (lane & 15)) * 32 + kof);
            #pragma unroll
            for (int mt = 0; mt < MT; ++mt)
                #pragma unroll
                for (int nt = 0; nt < NT; ++nt)
                    acc[mt][nt] = __builtin_amdgcn_mfma_f32_16x16x32_bf16(
                        af[mt], bf[nt], acc[mt][nt], 0, 0, 0);
            __syncthreads();
        }
    };

    kloop(A1, B1, K1);
    if (B2) kloop(A2, B2, K2);

    const int nb = tn * BN + wno + (lane & 15);
    const int mbl = wmo + ((lane >> 4) << 2);
    #pragma unroll
    for (int nt = 0; nt < NT; ++nt) {
        int n = nb + nt * 16;
        float bv = (EPI == 0) ? 0.f : bias[n];
        #pragma unroll
        for (int mt = 0; mt < MT; ++mt) {
            #pragma unroll
            for (int r = 0; r < 4; ++r) {
                int m = tm * 64 + mbl + mt * 16 + r;
                float v = acc[mt][nt][r] + bv;
                if constexpr (EPI == 0) {
                    int bb = m / 196, tok = m - bb * 196;
                    int reg = n >> 8, head = (n >> 5) & 7, d = n & 31;
                    out[((size_t)((reg * 512 + bb * 8 + head) * 196 + tok)) * 32 + d] = f2b(v);
                } else if constexpr (EPI == 1) {
                    out[(size_t)m * 768 + n] = f2b(v);
                } else if constexpr (EPI == 2) {
                    float gl = 0.5f * v * (1.f + erff(v * 0.70710678118654752f));
                    out[(size_t)m * 1536 + n] = f2b(gl);
                } else {
                    v += b2f(addend[(size_t)m * 768 + n]);
                    int mg = m + m_off;
                    int bb = mg / 196, tok = mg - bb * 196;
                    out[((size_t)(bb * 768 + n)) * 196 + tok] = v;   // fp32 store
                }
            }
        }
    }
}

// ---------------------------------------------------------------- launch
extern "C" void kernel_launch(void* const* d_in, const int* in_sizes, int n_in,
                              void* d_out, int out_size, void* d_ws, size_t ws_size,
                              hipStream_t stream) {
    const float* x       = (const float*)d_in[0];
    const float* W_qkv   = (const float*)d_in[1];
    const float* bias_tb = (const float*)d_in[2];
    const float* W_out   = (const float*)d_in[3];
    const float* b_out   = (const float*)d_in[4];
    const float* ln1_g   = (const float*)d_in[5];
    const float* ln1_b   = (const float*)d_in[6];
    const float* ln2_g   = (const float*)d_in[7];
    const float* ln2_b   = (const float*)d_in[8];
    const float* W_fc1   = (const float*)d_in[9];
    const float* b_fc1   = (const float*)d_in[10];
    const float* W_fc2   = (const float*)d_in[11];
    const float* b_fc2   = (const float*)d_in[12];
    const float* W_proj  = (const float*)d_in[13];
    float* out = (float*)d_out;

    char* ws = (char*)d_ws;
    ushortT* pooled = (ushortT*)(ws);                 // [12544][384]
    ushortT* tln1   = (ushortT*)(ws + 9633792);       // [12544][384]
    ushortT* attno  = tln1;                           // reuse
    ushortT* qkvb   = (ushortT*)(ws + 19267584);      // [3][64][8][196][32]
    ushortT* tln2   = qkvb;                           // reuse (after attn)
    ushortT* mid    = (ushortT*)(ws);                 // [6272][1536] reuse
    ushortT* htok   = (ushortT*)(ws + 38535168);      // [12544][768]
    // bias_exp [8][208][208] fp32 aliases the htok region: written by prep, read by
    // attn, then htok is written (by wout gemm) strictly AFTER attn -> stream-safe.
    float*   bias_exp = (float*)(ws + 38535168);      // 1,384,448 B
    ushortT* wTqkv  = (ushortT*)(ws + 57802752);      // [768][384]
    ushortT* wTout  = wTqkv + 768 * 384;              // [768][256]
    ushortT* wTfc1  = wTout + 768 * 256;              // [1536][768]
    ushortT* wTfc2  = wTfc1 + 1536 * 768;             // [768][1536]
    ushortT* wProjB = wTfc2 + 768 * 1536;             // [768][384]

    // merged weight prep + pool + bias expansion
    prep_pool<<<4946, 256, 0, stream>>>(W_qkv, W_out, W_fc1, W_fc2, W_proj, x, bias_tb,
                                        wTqkv, wTout, wTfc1, wTfc2, wProjB, pooled,
                                        bias_exp);

    // LN1
    ln_kernel<2><<<M_TOT / 4, 256, 0, stream>>>(pooled, ln1_g, ln1_b, tln1);

    // QKV gemm
    gemm64<128, 0, ushortT><<<dim3(196, 6), 256, 0, stream>>>(tln1, wTqkv, 384,
                                                nullptr, nullptr, 0,
                                                nullptr, nullptr, qkvb, 0);
    // MFMA attention
    attn_kernel<<<512, 256, 0, stream>>>(qkvb, bias_exp, attno);

    // h = attn_out @ W_out^T + pooled @ W_proj^T + b_out
    gemm64<128, 1, ushortT><<<dim3(196, 6), 256, 0, stream>>>(attno, wTout, 256,
                                                pooled, wProjB, 384,
                                                b_out, nullptr, htok, 0);
    // LN2
    ln_kernel<4><<<M_TOT / 4, 256, 0, stream>>>(htok, ln2_g, ln2_b, tln2);

    // FFN in two M-halves
    for (int half = 0; half < 2; ++half) {
        const ushortT* a2 = tln2 + (size_t)half * M_HALF * 768;
        gemm64<128, 2, ushortT><<<dim3(98, 12), 256, 0, stream>>>(a2, wTfc1, 768,
                                                     nullptr, nullptr, 0,
                                                     b_fc1, nullptr, mid, 0);
        gemm64<64, 3, float><<<dim3(98, 12), 256, 0, stream>>>(mid, wTfc2, 1536,
                                                    nullptr, nullptr, 0,
                                                    b_fc2, htok + (size_t)half * M_HALF * 768,
                                                    out, half * M_HALF);
    }
    (void)in_sizes; (void)n_in; (void)out_size; (void)ws_size;
}